// Round 9
// baseline (573.774 us; speedup 1.0000x reference)
//
#include <hip/hip_runtime.h>
#include <stdint.h>

typedef __attribute__((ext_vector_type(4))) float f32x4;
typedef __attribute__((ext_vector_type(2))) unsigned int u32x2;
typedef __attribute__((ext_vector_type(4))) unsigned int u32x4;
typedef __attribute__((ext_vector_type(8))) short bf16x8;

#define BV (128*40000)

__device__ __forceinline__ unsigned rne_bf16(float f) {
    unsigned x = __float_as_uint(f);
    return ((x + 0x7FFFu + ((x >> 16) & 1u)) >> 16) & 0xFFFFu;
}
__device__ __forceinline__ unsigned pack2(float a, float b) {
    return rne_bf16(a) | (rne_bf16(b) << 16);
}
__device__ __forceinline__ float bf2f(unsigned u) {
    return __uint_as_float((u & 0xFFFFu) << 16);
}
__device__ __forceinline__ float sigm(float x) { return 1.0f / (1.0f + expf(-x)); }
__device__ __forceinline__ float ftanh(float x) {
    float e = __expf(2.0f * x);
    return 1.0f - 2.0f / (e + 1.0f);
}

__device__ __forceinline__ void gload16(const void* g, void* l) {
    __builtin_amdgcn_global_load_lds(
        (const __attribute__((address_space(1))) unsigned*)g,
        (__attribute__((address_space(3))) unsigned*)l, 16, 0, 0);
}

// ---------------------------------------------------------------------------
// Persistent 256x256 bf16 MFMA GEMM, 4-phase interleaved counted-vmcnt
// pipeline, dynamic tile queue (verified R7/R8 GEMM structure).
// Queue: 0..11 qh (cls4, f32 store + release flag) | 12..51 att (cls0, spin)
//        52..91 stac (cls1, bf16 store) | 92..cvtb-1 hist (cls2, spin)
//        cvtb.. W_ih/W_hh bf16 conversion tiles (cls5, pure memory)
// ---------------------------------------------------------------------------
struct BigArgs {
    const unsigned short *hs, *WmhT, *se, *ae, *WmsT, *WmaT, *WmscT;
    const unsigned short *q0, *Wq0T, *Wq1T, *Wq2T;
    const float *Wihf, *Whhf;
    unsigned short *WihB, *WhhB;
    const float *bq_h, *v_h, *bq_s, *v_s, *bq_a, *v_a;
    float *qh_h, *qh_s, *qh_a;
    float *hsc, *stsc, *acsc;
    unsigned short *mseh, *maeh;
};

__global__ __launch_bounds__(512, 1) void k_big(
    BigArgs a, int* __restrict__ ctr, int* __restrict__ dqh,
    const int* __restrict__ prefix, const int* __restrict__ ntp) {
    __shared__ unsigned short As[2][16384];
    __shared__ unsigned short Bs[2][16384];
    __shared__ int sTile;
    __shared__ int rows_tab[256];

    const int nTiles = ntp[0], Mp = ntp[1], cvtb = ntp[2];
    const int t = threadIdx.x, lane = t & 63, wv = t >> 6;
    const int l16 = lane & 15, lq = lane >> 4;
    const int wm = wv >> 2, wn = wv & 3;
    const int srowL = t >> 3;
    const int gccA = ((t & 7) ^ (srowL & 7)) << 3;
    const int swz = l16 & 7;
    const int c0 = ((lq ^ swz) << 3);
    const int A0 = (wm << 13) + (l16 << 6);
    const int B0 = ((wn >> 1) << 13) + ((((wn & 1) << 6) + l16) << 6);

#define STQA(ktt, d, q) gload16(gAr[q] + (ktt) * 64, &As[d][((q) << 12) + (wv << 9)])
#define STQB(ktt, d, q) gload16(gB + ((size_t)(q) << 16) + (ktt) * 64, &Bs[d][((q) << 12) + (wv << 9)])

    for (;;) {
        __syncthreads();
        if (t == 0) sTile = atomicAdd(ctr, 1);
        __syncthreads();
        const int wg = sTile;
        if (wg >= nTiles) return;

        // ---- cls5: W_ih/W_hh bf16 conversion tiles (tail filler) ----
        if (wg >= cvtb) {
            const int G_IH = 1572864;                 // W_ih u32x4-groups
            int g0 = (wg - cvtb) * 30720 + t;
#pragma unroll 4
            for (int it = 0; it < 60; ++it, g0 += 512) {
                const f32x4* s4;
                u32x4* d4;
                if (g0 < G_IH) { s4 = (const f32x4*)a.Wihf + (size_t)g0 * 2; d4 = (u32x4*)a.WihB + g0; }
                else { int g2 = g0 - G_IH; s4 = (const f32x4*)a.Whhf + (size_t)g2 * 2; d4 = (u32x4*)a.WhhB + g2; }
                f32x4 q0 = s4[0], q1 = s4[1];
                *d4 = (u32x4){pack2(q0[0],q0[1]), pack2(q0[2],q0[3]), pack2(q1[0],q1[1]), pack2(q1[2],q1[3])};
            }
            continue;
        }

        const unsigned short *Abase, *Bt;
        const float *rb = nullptr, *cb = nullptr, *vv = nullptr;
        float* out = nullptr;
        unsigned short* outh = nullptr;
        int m0, n0, vrows, cls;
        if (wg < 12) {
            cls = 4;
            int op = wg >> 2;
            Abase = a.q0;
            Bt = (op == 0) ? a.Wq0T : (op == 1) ? a.Wq1T : a.Wq2T;
            out = (op == 0) ? a.qh_h : (op == 1) ? a.qh_s : a.qh_a;
            m0 = 0; n0 = (wg & 3) << 8; vrows = 128;
        } else if (wg < 52) {
            cls = 0;
            int r = wg - 12;
            int op = r / 20; r -= op * 20;
            int mt = r >> 2, nt2 = r & 3;
            if (op == 0) { Abase = a.se; Bt = a.WmsT; rb = a.qh_s; cb = a.bq_s; vv = a.v_s; out = a.stsc; }
            else         { Abase = a.ae; Bt = a.WmaT; rb = a.qh_a; cb = a.bq_a; vv = a.v_a; out = a.acsc; }
            m0 = mt << 8; n0 = nt2 << 8; vrows = 256;
        } else if (wg < 92) {
            cls = 1;
            int r = wg - 52;
            int op = r / 20; r -= op * 20;
            int mt = r >> 2, nt2 = r & 3;
            Abase = op ? a.ae : a.se; Bt = a.WmscT;
            outh = op ? a.maeh : a.mseh;
            m0 = mt << 8; n0 = nt2 << 8; vrows = 256;
        } else {
            cls = 2;
            int h = wg - 92;
            int m = h >> 2, n = h & 3;
            Abase = a.hs; Bt = a.WmhT; rb = a.qh_h; cb = a.bq_h; vv = a.v_h; out = a.hsc;
            m0 = m << 8; n0 = n << 8;
            vrows = Mp - m0; if (vrows > 256) vrows = 256;
        }

        if (t < 256) {
            int rid;
            if (cls != 2) {
                rid = m0 + t;
            } else {
                int g = m0 + t;
                if (g < Mp) {
                    int lo = 0, hi = 128;
                    while (hi - lo > 1) {
                        int mid = (lo + hi) >> 1;
                        if (prefix[mid] <= g) lo = mid; else hi = mid;
                    }
                    rid = (lo << 8) + (g - prefix[lo]);
                } else {
                    rid = 0;
                }
            }
            rows_tab[t] = rid;
        }
        __syncthreads();

        const unsigned short* gAr[4];
#pragma unroll
        for (int q = 0; q < 4; ++q)
            gAr[q] = Abase + ((size_t)rows_tab[srowL + (q << 6)] << 10) + gccA;
        const unsigned short* gB = Bt + (size_t)(n0 + srowL) * 1024 + gccA;

        f32x4 acc[8][4];
#pragma unroll
        for (int i = 0; i < 8; ++i)
#pragma unroll
            for (int j = 0; j < 4; ++j) acc[i][j] = (f32x4){0.f, 0.f, 0.f, 0.f};

        // prologue: stage kt0 in L-order
        STQA(0, 0, 0); STQA(0, 0, 2);
        STQB(0, 0, 0); STQB(0, 0, 1); STQB(0, 0, 2); STQB(0, 0, 3);
        STQA(0, 0, 1); STQA(0, 0, 3);
        __builtin_amdgcn_sched_barrier(0);
        asm volatile("s_waitcnt vmcnt(2)" ::: "memory");
        __builtin_amdgcn_s_barrier();

        for (int kt = 0; kt < 16; ++kt) {
            const int cur = kt & 1, dn = cur ^ 1, kn = kt + 1;
            const bool pre = kt < 15;
            const unsigned short* ab = As[cur];
            const unsigned short* bb = Bs[cur];
            bf16x8 bk0[4], bk1[4], af[4];
            // ---- ph0 ----
            if (pre) { STQA(kn, dn, 0); STQA(kn, dn, 2); }
#pragma unroll
            for (int nf = 0; nf < 4; ++nf) bk0[nf] = *(const bf16x8*)(bb + B0 + (nf << 10) + c0);
#pragma unroll
            for (int mf = 0; mf < 4; ++mf) af[mf] = *(const bf16x8*)(ab + A0 + (mf << 10) + c0);
            __builtin_amdgcn_s_setprio(1);
#pragma unroll
            for (int mf = 0; mf < 4; ++mf)
#pragma unroll
                for (int nf = 0; nf < 4; ++nf)
                    acc[mf][nf] = __builtin_amdgcn_mfma_f32_16x16x32_bf16(af[mf], bk0[nf], acc[mf][nf], 0, 0, 0);
            __builtin_amdgcn_s_setprio(0);
            // ---- ph1 ----
            if (pre) { STQB(kn, dn, 0); STQB(kn, dn, 1); }
#pragma unroll
            for (int nf = 0; nf < 4; ++nf) bk1[nf] = *(const bf16x8*)(bb + B0 + (nf << 10) + (c0 ^ 32));
#pragma unroll
            for (int mf = 0; mf < 4; ++mf) af[mf] = *(const bf16x8*)(ab + A0 + (mf << 10) + (c0 ^ 32));
            __builtin_amdgcn_s_setprio(1);
#pragma unroll
            for (int mf = 0; mf < 4; ++mf)
#pragma unroll
                for (int nf = 0; nf < 4; ++nf)
                    acc[mf][nf] = __builtin_amdgcn_mfma_f32_16x16x32_bf16(af[mf], bk1[nf], acc[mf][nf], 0, 0, 0);
            __builtin_amdgcn_s_setprio(0);
            // ---- pre-mid stage + mid wait ----
            if (pre) { STQB(kn, dn, 2); STQB(kn, dn, 3); }
            __builtin_amdgcn_sched_barrier(0);
            if (pre) asm volatile("s_waitcnt vmcnt(6)" ::: "memory");
            else     asm volatile("s_waitcnt vmcnt(0)" ::: "memory");
            __builtin_amdgcn_s_barrier();
            // ---- ph2 ----
#pragma unroll
            for (int mf = 0; mf < 4; ++mf) af[mf] = *(const bf16x8*)(ab + A0 + ((4 + mf) << 10) + c0);
            __builtin_amdgcn_s_setprio(1);
#pragma unroll
            for (int mf = 0; mf < 4; ++mf)
#pragma unroll
                for (int nf = 0; nf < 4; ++nf)
                    acc[4 + mf][nf] = __builtin_amdgcn_mfma_f32_16x16x32_bf16(af[mf], bk0[nf], acc[4 + mf][nf], 0, 0, 0);
            __builtin_amdgcn_s_setprio(0);
            // ---- ph3 ----
            if (pre) { STQA(kn, dn, 1); STQA(kn, dn, 3); }
#pragma unroll
            for (int mf = 0; mf < 4; ++mf) af[mf] = *(const bf16x8*)(ab + A0 + ((4 + mf) << 10) + (c0 ^ 32));
            __builtin_amdgcn_s_setprio(1);
#pragma unroll
            for (int mf = 0; mf < 4; ++mf)
#pragma unroll
                for (int nf = 0; nf < 4; ++nf)
                    acc[4 + mf][nf] = __builtin_amdgcn_mfma_f32_16x16x32_bf16(af[mf], bk1[nf], acc[4 + mf][nf], 0, 0, 0);
            __builtin_amdgcn_s_setprio(0);
            // ---- boundary wait ----
            __builtin_amdgcn_sched_barrier(0);
            if (pre) asm volatile("s_waitcnt vmcnt(2)" ::: "memory");
            else     asm volatile("s_waitcnt vmcnt(0)" ::: "memory");
            __builtin_amdgcn_s_barrier();
        }

        if (cls == 1) {
            int gcs4[4];
#pragma unroll
            for (int nf = 0; nf < 4; ++nf) gcs4[nf] = n0 + (wn << 6) + (nf << 4) + l16;
#pragma unroll
            for (int mf = 0; mf < 8; ++mf) {
#pragma unroll
                for (int r = 0; r < 4; ++r) {
                    int grow = m0 + (wm << 7) + (mf << 4) + (lq << 2) + r;
#pragma unroll
                    for (int nf = 0; nf < 4; ++nf)
                        outh[(size_t)grow * 1024 + gcs4[nf]] = (unsigned short)rne_bf16(acc[mf][nf][r]);
                }
            }
        } else if (cls == 4) {
            // f32 store of q0@Wq, then release the done flag
#pragma unroll
            for (int mf = 0; mf < 8; ++mf) {
                int rloc = (wm << 7) + (mf << 4);
                if (rloc < vrows) {
#pragma unroll
                    for (int r = 0; r < 4; ++r) {
                        int gr = rloc + (lq << 2) + r;
#pragma unroll
                        for (int nf = 0; nf < 4; ++nf) {
                            int gc = n0 + (wn << 6) + (nf << 4) + l16;
                            out[(size_t)gr * 1024 + gc] = acc[mf][nf][r];
                        }
                    }
                }
            }
            __threadfence();
            __syncthreads();
            if (t == 0) atomicAdd(dqh, 1);
        } else {
            // acquire: wait until all 12 qh tiles have stored
            if (t == 0) { while (atomicAdd(dqh, 0) < 12) { } }
            __syncthreads();
            float cbv[4], vvv[4];
            int gcs[4];
#pragma unroll
            for (int nf = 0; nf < 4; ++nf) {
                int gc = n0 + (wn << 6) + (nf << 4) + l16;
                gcs[nf] = gc; cbv[nf] = cb[gc]; vvv[nf] = vv[gc];
            }
#pragma unroll
            for (int mf = 0; mf < 8; ++mf) {
                int rloc = (wm << 7) + (mf << 4);
                if (rloc < vrows) {
#pragma unroll
                    for (int r = 0; r < 4; ++r) {
                        int lrow = rloc + (lq << 2) + r;
                        if (lrow >= vrows) continue;
                        int gr = m0 + lrow;
                        int bidx = (cls == 2) ? (rows_tab[lrow] >> 8) : (gr / 10);
                        const float* rbp = rb + ((size_t)bidx << 10);
                        float s = 0.f;
#pragma unroll
                        for (int nf = 0; nf < 4; ++nf) {
                            float x = acc[mf][nf][r] + rbp[gcs[nf]] + cbv[nf];
                            s += ftanh(x) * vvv[nf];
                        }
#pragma unroll
                        for (int m2 = 1; m2 < 16; m2 <<= 1) s += __shfl_xor(s, m2, 64);
                        if (l16 == 0) atomicAdd(&out[gr], s);
                    }
                }
            }
        }
    }
#undef STQA
#undef STQB
}

// ---------------------------------------------------------------------------
// m97-style 128x128 bf16 MFMA GEMM, split-K atomic (GRU gate GEMMs).
// ---------------------------------------------------------------------------
__device__ __forceinline__ void mgemm2(
    const unsigned short* __restrict__ A, const unsigned short* __restrict__ Bt,
    float* __restrict__ out,
    int m0, int n0, int kb, int ke, int ldk, int ldc)
{
    __shared__ unsigned short As[2][4096];
    __shared__ unsigned short Bs[2][4096];
    const int t = threadIdx.x, lane = t & 63, wv = t >> 6;
    const int l16 = lane & 15, lq = lane >> 4;
    const int wm = wv >> 1, wn = wv & 1;

    const int srow = lane >> 2, scol = (lane & 3) << 3;
    const unsigned short* gA0 = A + (size_t)(m0 + (wv << 4) + srow) * ldk + kb + scol;
    const unsigned short* gA1 = gA0 + (size_t)64 * ldk;
    const unsigned short* gB0 = Bt + (size_t)(n0 + (wv << 4) + srow) * ldk + kb + scol;
    const unsigned short* gB1 = gB0 + (size_t)64 * ldk;
    unsigned short* lA0 = &As[0][wv << 9];
    unsigned short* lA1 = &As[0][(wv + 4) << 9];
    unsigned short* lB0 = &Bs[0][wv << 9];
    unsigned short* lB1 = &Bs[0][(wv + 4) << 9];

    f32x4 acc[4][4];
#pragma unroll
    for (int i = 0; i < 4; ++i)
#pragma unroll
        for (int j = 0; j < 4; ++j) acc[i][j] = (f32x4){0.f, 0.f, 0.f, 0.f};

    const int NS = (ke - kb) >> 5;
    gload16(gA0, lA0); gload16(gA1, lA1);
    gload16(gB0, lB0); gload16(gB1, lB1);

    for (int s = 0; s < NS; ++s) {
        __syncthreads();
        if (s + 1 < NS) {
            const int nb = (s + 1) & 1, ko = (s + 1) << 5;
            gload16(gA0 + ko, lA0 + (nb << 12)); gload16(gA1 + ko, lA1 + (nb << 12));
            gload16(gB0 + ko, lB0 + (nb << 12)); gload16(gB1 + ko, lB1 + (nb << 12));
        }
        const unsigned short* ab = As[s & 1];
        const unsigned short* bb = Bs[s & 1];
        bf16x8 af[4], bfv[4];
#pragma unroll
        for (int i = 0; i < 4; ++i)
            af[i] = *(const bf16x8*)(ab + (((wm << 6) + (i << 4) + l16) << 5) + (lq << 3));
#pragma unroll
        for (int i = 0; i < 4; ++i)
            bfv[i] = *(const bf16x8*)(bb + (((wn << 6) + (i << 4) + l16) << 5) + (lq << 3));
#pragma unroll
        for (int mf = 0; mf < 4; ++mf)
#pragma unroll
            for (int nf = 0; nf < 4; ++nf)
                acc[mf][nf] = __builtin_amdgcn_mfma_f32_16x16x32_bf16(af[mf], bfv[nf], acc[mf][nf], 0, 0, 0);
    }

#pragma unroll
    for (int mf = 0; mf < 4; ++mf) {
        int gr0 = m0 + (wm << 6) + (mf << 4) + (lq << 2);
#pragma unroll
        for (int nf = 0; nf < 4; ++nf) {
            int gc = n0 + (wn << 6) + (nf << 4) + l16;
#pragma unroll
            for (int r = 0; r < 4; ++r)
                atomicAdd(&out[(size_t)(gr0 + r) * ldc + gc], acc[mf][nf][r]);
        }
    }
}

// gene logits: A = hnew bf16 (gload_lds), B = W_out f32 KxN (reg-stage cvt)
__device__ __forceinline__ void gene_body(
    const unsigned short* __restrict__ hnb, const float* __restrict__ Wout,
    const float* __restrict__ b_out, float* __restrict__ out, int n0)
{
    __shared__ unsigned short As[2][4096];
    __shared__ unsigned short Bs[2][4096];
    const int t = threadIdx.x, lane = t & 63, wv = t >> 6;
    const int l16 = lane & 15, lq = lane >> 4;
    const int wm = wv >> 1, wn = wv & 1;

    const int srow = lane >> 2, scol = (lane & 3) << 3;
    const unsigned short* gA0 = hnb + (size_t)((wv << 4) + srow) * 1024 + scol;
    const unsigned short* gA1 = gA0 + (size_t)64 * 1024;
    unsigned short* lA0 = &As[0][wv << 9];
    unsigned short* lA1 = &As[0][(wv + 4) << 9];

    const int bn = t & 127, kh = t >> 7;
    const bool ok = (n0 + bn) < 40000;
    const float* gB = Wout + (size_t)(kh * 16) * 40000 + (n0 + bn);

    f32x4 acc[4][4];
#pragma unroll
    for (int i = 0; i < 4; ++i)
#pragma unroll
        for (int j = 0; j < 4; ++j) acc[i][j] = (f32x4){0.f, 0.f, 0.f, 0.f};

    auto stageB = [&](int buf, int ko) {
        const float* src = gB + (size_t)ko * 40000;
        float f[16];
#pragma unroll
        for (int j = 0; j < 16; ++j) f[j] = ok ? src[(size_t)j * 40000] : 0.0f;
        u32x4* d = (u32x4*)&Bs[buf][bn * 32 + kh * 16];
        d[0] = (u32x4){pack2(f[0],f[1]), pack2(f[2],f[3]), pack2(f[4],f[5]), pack2(f[6],f[7])};
        d[1] = (u32x4){pack2(f[8],f[9]), pack2(f[10],f[11]), pack2(f[12],f[13]), pack2(f[14],f[15])};
    };

    gload16(gA0, lA0); gload16(gA1, lA1); stageB(0, 0);
    for (int s = 0; s < 32; ++s) {
        __syncthreads();
        if (s + 1 < 32) {
            const int nb = (s + 1) & 1, ko = (s + 1) << 5;
            gload16(gA0 + ko, lA0 + (nb << 12)); gload16(gA1 + ko, lA1 + (nb << 12));
            stageB(nb, ko);
        }
        const unsigned short* ab = As[s & 1];
        const unsigned short* bb = Bs[s & 1];
        bf16x8 af[4], bfv[4];
#pragma unroll
        for (int i = 0; i < 4; ++i)
            af[i] = *(const bf16x8*)(ab + (((wm << 6) + (i << 4) + l16) << 5) + (lq << 3));
#pragma unroll
        for (int i = 0; i < 4; ++i)
            bfv[i] = *(const bf16x8*)(bb + (((wn << 6) + (i << 4) + l16) << 5) + (lq << 3));
#pragma unroll
        for (int mf = 0; mf < 4; ++mf)
#pragma unroll
            for (int nf = 0; nf < 4; ++nf)
                acc[mf][nf] = __builtin_amdgcn_mfma_f32_16x16x32_bf16(af[mf], bfv[nf], acc[mf][nf], 0, 0, 0);
    }
#pragma unroll
    for (int mf = 0; mf < 4; ++mf) {
        int gr0 = (wm << 6) + (mf << 4) + (lq << 2);
#pragma unroll
        for (int nf = 0; nf < 4; ++nf) {
            int gc = n0 + (wn << 6) + (nf << 4) + l16;
            if (gc < 40000) {
                float bo = b_out[gc];
#pragma unroll
                for (int r = 0; r < 4; ++r)
                    out[(size_t)(gr0 + r) * 40000 + gc] = acc[mf][nf][r] + bo;
            }
        }
    }
}

// ------------------------------ GEMM wrappers ------------------------------
__global__ __launch_bounds__(256) void k_gigh2(
    const unsigned short* xb, const unsigned short* q0,
    const unsigned short* Wih, const unsigned short* Whh, float* gi, float* gh) {
    if (blockIdx.z == 0) {
        int kb = blockIdx.y << 9;
        mgemm2(xb, Wih, gi, 0, blockIdx.x * 128, kb, kb + 512, 4096, 3072);
    } else {
        if (blockIdx.y >= 2) return;
        int kb = blockIdx.y << 9;
        mgemm2(q0, Whh, gh, 0, blockIdx.x * 128, kb, kb + 512, 1024, 3072);
    }
}

// gene logits (313 blocks) + R = weighted gumbel-prob sums (5120 blocks)
__global__ __launch_bounds__(256) void k_geneR(
    const unsigned short* __restrict__ hnb, const float* __restrict__ Wout,
    const float* __restrict__ b_out, float* __restrict__ out,
    const float* __restrict__ sprob, const float* __restrict__ aprob,
    const float* __restrict__ stlg, const float* __restrict__ aclg,
    const float* __restrict__ mtil, float* __restrict__ R) {
    int id = blockIdx.x;
    if (id < 313) {
        gene_body(hnb, Wout, b_out, out, id << 7);
        return;
    }
    int rid = id - 313;
    int b = rid / 40, ch = rid - b * 40;
    int t = threadIdx.x;
    __shared__ float wsb[20];
    if (t < 10) wsb[t] = expf(stlg[b * 10 + t] - mtil[b]);
    else if (t < 20) wsb[t] = expf(aclg[b * 10 + (t - 10)] - mtil[b]);
    __syncthreads();
    if (t >= 250) return;
    int v4 = ch * 250 + t;
    size_t base = (size_t)b * 10000 + v4;
    f32x4 r = {0.f, 0.f, 0.f, 0.f};
#pragma unroll
    for (int s = 0; s < 10; ++s) {
        f32x4 pv = ((const f32x4*)sprob)[((size_t)b * 10 + s) * 10000 + v4];
        f32x4 av = ((const f32x4*)aprob)[((size_t)b * 10 + s) * 10000 + v4];
        float ws = wsb[s], wa = wsb[10 + s];
#pragma unroll
        for (int j = 0; j < 4; ++j) r[j] += ws * pv[j] + wa * av[j];
    }
    ((f32x4*)R)[base] = r;
}

// --------------------------- prep kernel ------------------------------------
struct PrepArgs {
    const float* cs[4]; unsigned short* cd[4]; int pre[5];
    const float* ts[8]; unsigned short* td[8];
    const int* lens; int* prefix; int* nt;
};
__global__ __launch_bounds__(256) void k_prep(PrepArgs a) {
    int bid = blockIdx.x, t = threadIdx.x;
    if (bid < 2048) {
        __shared__ float tile[64][65];
        int z = bid >> 8, rem = bid & 255, y = rem >> 4, x = rem & 15;
        const float* in = a.ts[z];
        unsigned short* ot = a.td[z];
        int k0 = y << 6, n0 = x << 6;
        int tr = t >> 6, tc = t & 63;
#pragma unroll
        for (int i = 0; i < 16; ++i) {
            int r = (i << 2) + tr;
            tile[r][tc] = in[(size_t)(k0 + r) * 1024 + n0 + tc];
        }
        __syncthreads();
#pragma unroll
        for (int i = 0; i < 16; ++i) {
            int r = (i << 2) + tr;
            ot[(size_t)(n0 + r) * 1024 + k0 + tc] = (unsigned short)rne_bf16(tile[tc][r]);
        }
    } else if (bid == 2048) {
        __shared__ int sc[128];
        if (t < 128) sc[t] = a.lens[t];
        __syncthreads();
        for (int off = 1; off < 128; off <<= 1) {
            int x = (t >= off && t < 128) ? sc[t - off] : 0;
            __syncthreads();
            if (t < 128) sc[t] += x;
            __syncthreads();
        }
        if (t == 0) a.prefix[0] = 0;
        if (t < 128) a.prefix[t + 1] = sc[t];
        if (t == 127) {
            int Mp = sc[127];
            int H4 = ((Mp + 255) >> 8) << 2;
            a.nt[0] = 92 + H4 + 64;   // total tiles
            a.nt[1] = Mp;
            a.nt[2] = 92 + H4;        // cvt base
        }
    } else {
        int total = a.pre[4];
        for (int i = (bid - 2049) * 256 + t; i < total; i += 2048 * 256) {
            int seg = 0;
            while (i >= a.pre[seg + 1]) ++seg;
            int loc = i - a.pre[seg];
            const f32x4* s4 = (const f32x4*)a.cs[seg] + (size_t)loc * 2;
            f32x4 q0 = s4[0], q1 = s4[1];
            ((u32x4*)a.cd[seg])[loc] =
                (u32x4){pack2(q0[0],q0[1]), pack2(q0[2],q0[3]), pack2(q1[0],q1[1]), pack2(q1[2],q1[3])};
        }
    }
}

// --------------------------- non-GEMM kernels ------------------------------
__device__ __forceinline__ void softmax10(const float* src, float* dst) {
    float m = src[0];
    for (int i = 1; i < 10; ++i) m = fmaxf(m, src[i]);
    float z = 0.f, e[10];
    for (int i = 0; i < 10; ++i) { e[i] = expf(src[i] - m); z += e[i]; }
    float iz = 1.0f / z;
    for (int i = 0; i < 10; ++i) dst[i] = e[i] * iz;
}

__global__ __launch_bounds__(256) void k_ctx(
    const float* __restrict__ scores, const int* __restrict__ lens,
    const int* __restrict__ prefix,
    const unsigned short* __restrict__ hs,
    const float* __restrict__ inp, const float* __restrict__ st_sc, const float* __restrict__ ac_sc,
    const unsigned short* __restrict__ se, const unsigned short* __restrict__ ae,
    unsigned short* __restrict__ xb) {
    int b = blockIdx.x, t = threadIdx.x;
    __shared__ float w[256];
    __shared__ float red[256];
    __shared__ float sw[10], aw[10];
    int len = lens[b];
    int base = prefix[b];
    bool valid = t < len;
    float s = valid ? scores[base + t] : -3.0e38f;
    red[t] = s;
    __syncthreads();
    for (int st = 128; st > 0; st >>= 1) { if (t < st) red[t] = fmaxf(red[t], red[t + st]); __syncthreads(); }
    float m = red[0];
    __syncthreads();
    float e = valid ? expf(s - m) : 0.0f;
    red[t] = e;
    __syncthreads();
    for (int st = 128; st > 0; st >>= 1) { if (t < st) red[t] += red[t + st]; __syncthreads(); }
    float Z = red[0];
    __syncthreads();
    w[t] = e / Z;
    if (t == 0) softmax10(st_sc + b * 10, sw);
    if (t == 64) softmax10(ac_sc + b * 10, aw);
    f32x4 iv = ((const f32x4*)(inp + (size_t)b * 1024))[t];
    *((u32x2*)(xb + (size_t)b * 4096) + t) = (u32x2){pack2(iv[0], iv[1]), pack2(iv[2], iv[3])};
    __syncthreads();
    float a0 = 0.f, a1 = 0.f, a2 = 0.f, a3 = 0.f;
    for (int l = 0; l < 256; ++l) {
        float wl = w[l];
        if (wl == 0.0f) continue;
        u32x2 u = *((const u32x2*)(hs + ((size_t)b * 256 + l) * 1024) + t);
        a0 += wl * bf2f(u[0]); a1 += wl * bf2f(u[0] >> 16);
        a2 += wl * bf2f(u[1]); a3 += wl * bf2f(u[1] >> 16);
    }
    *((u32x2*)(xb + (size_t)b * 4096 + 1024) + t) = (u32x2){pack2(a0, a1), pack2(a2, a3)};
    float cs0=0,cs1=0,cs2=0,cs3=0, ca0=0,ca1=0,ca2=0,ca3=0;
#pragma unroll
    for (int q = 0; q < 10; ++q) {
        u32x2 us = *((const u32x2*)(se + ((size_t)b * 10 + q) * 1024) + t);
        u32x2 ua = *((const u32x2*)(ae + ((size_t)b * 10 + q) * 1024) + t);
        float ws = sw[q], wa = aw[q];
        cs0 += ws * bf2f(us[0]); cs1 += ws * bf2f(us[0] >> 16);
        cs2 += ws * bf2f(us[1]); cs3 += ws * bf2f(us[1] >> 16);
        ca0 += wa * bf2f(ua[0]); ca1 += wa * bf2f(ua[0] >> 16);
        ca2 += wa * bf2f(ua[1]); ca3 += wa * bf2f(ua[1] >> 16);
    }
    *((u32x2*)(xb + (size_t)b * 4096 + 2048) + t) = (u32x2){pack2(cs0, cs1), pack2(cs2, cs3)};
    *((u32x2*)(xb + (size_t)b * 4096 + 3072) + t) = (u32x2){pack2(ca0, ca1), pack2(ca2, ca3)};
}

// GRU elementwise + hs_logits + (y==0: qsc GEMV in LDS + stac logits + mtil)
__global__ __launch_bounds__(1024) void k_gruhsl(
    const float* __restrict__ gi, const float* __restrict__ gh,
    const float* __restrict__ b_ih, const float* __restrict__ b_hh,
    const float* __restrict__ h0, float* __restrict__ hnew,
    unsigned short* __restrict__ hnb,
    const unsigned short* __restrict__ hs, float* __restrict__ hsl,
    const unsigned short* __restrict__ WqscT,
    const unsigned short* __restrict__ mseh, const unsigned short* __restrict__ maeh,
    const float* __restrict__ bq_sc, const float* __restrict__ v_sc,
    const float* __restrict__ tagrow,
    float* __restrict__ stlg, float* __restrict__ aclg, float* __restrict__ mtil) {
    int b = blockIdx.x, y = blockIdx.y, j = threadIdx.x;
    size_t i = (size_t)b * 1024 + j;
    const float* gib = gi + (size_t)b * 3072;
    const float* ghb = gh + (size_t)b * 3072;
    float r = sigm(gib[j] + b_ih[j] + ghb[j] + b_hh[j]);
    float z = sigm(gib[1024 + j] + b_ih[1024 + j] + ghb[1024 + j] + b_hh[1024 + j]);
    float hn = ghb[2048 + j] + b_hh[2048 + j];
    float n = tanhf(gib[2048 + j] + b_ih[2048 + j] + r * hn);
    float h = (1.0f - z) * n + z * h0[i];
    __shared__ float hsm[1024];
    __shared__ float qs[1024];
    __shared__ float res[20];
    if (y == 0) {
        hnew[i] = h;
        hnb[i] = (unsigned short)rne_bf16(h);
    }
    hsm[j] = h;
    __syncthreads();              // S1
    if (y == 0) {
        float acn = 0.f;
        const u32x4* wr = (const u32x4*)(WqscT + ((size_t)j << 10));
#pragma unroll 4
        for (int k8 = 0; k8 < 128; ++k8) {
            u32x4 u = wr[k8];
            const float* hp = hsm + (k8 << 3);
            acn += hp[0]*bf2f(u[0]) + hp[1]*bf2f(u[0]>>16)
                 + hp[2]*bf2f(u[1]) + hp[3]*bf2f(u[1]>>16)
                 + hp[4]*bf2f(u[2]) + hp[5]*bf2f(u[2]>>16)
                 + hp[6]*bf2f(u[3]) + hp[7]*bf2f(u[3]>>16);
        }
        qs[j] = acn + bq_sc[j];
    }
    __syncthreads();              // S2
    int wave = j >> 6, lane = j & 63;
    if (y == 0) {
        for (int rr = wave; rr < 20; rr += 16) {
            bool ac = rr >= 10;
            int s5 = ac ? rr - 10 : rr;
            const unsigned short* mm = (ac ? maeh : mseh) + ((size_t)b * 10 + s5) * 1024;
            float acc2 = 0.f;
#pragma unroll
            for (int k2 = 0; k2 < 16; ++k2) {
                int c = lane + (k2 << 6);
                float x = bf2f(mm[c]) + qs[c];
                if (ac) x += tagrow[c];
                acc2 += ftanh(x) * v_sc[c];
            }
#pragma unroll
            for (int m2 = 1; m2 < 64; m2 <<= 1) acc2 += __shfl_xor(acc2, m2, 64);
            if (lane == 0) res[rr] = acc2;
        }
    }
    __syncthreads();              // S3
    if (y == 0) {
        if (j < 10) stlg[b * 10 + j] = res[j];
        if (j >= 64 && j < 74) aclg[b * 10 + (j - 64)] = res[10 + (j - 64)];
        if (j == 128) {
            float mt = res[0];
            for (int i2 = 1; i2 < 20; ++i2) mt = fmaxf(mt, res[i2]);
            mtil[b] = mt;
        }
    }
    float hr[16];
#pragma unroll
    for (int k = 0; k < 16; ++k) hr[k] = hsm[lane * 16 + k];
    for (int l = (y << 7) + wave; l < (y << 7) + 128; l += 16) {
        const u32x4* row = (const u32x4*)(hs + ((size_t)b * 256 + l) * 1024);
        u32x4 u0 = row[lane * 2], u1 = row[lane * 2 + 1];
        float s = hr[0]*bf2f(u0[0]) + hr[1]*bf2f(u0[0]>>16) + hr[2]*bf2f(u0[1]) + hr[3]*bf2f(u0[1]>>16)
                + hr[4]*bf2f(u0[2]) + hr[5]*bf2f(u0[2]>>16) + hr[6]*bf2f(u0[3]) + hr[7]*bf2f(u0[3]>>16)
                + hr[8]*bf2f(u1[0]) + hr[9]*bf2f(u1[0]>>16) + hr[10]*bf2f(u1[1]) + hr[11]*bf2f(u1[1]>>16)
                + hr[12]*bf2f(u1[2]) + hr[13]*bf2f(u1[2]>>16) + hr[14]*bf2f(u1[3]) + hr[15]*bf2f(u1[3]>>16);
#pragma unroll
        for (int msk = 1; msk < 64; msk <<= 1) s += __shfl_xor(s, msk, 64);
        if (lane == 0) hsl[b * 256 + l] = s;
    }
}

// softmax stats over concat + copy_p scatter; one block per b
__global__ __launch_bounds__(256) void k_smsc(
    const float* __restrict__ gene, const float* __restrict__ hsl,
    const float* __restrict__ stl, const float* __restrict__ acl,
    const int* __restrict__ hwi,
    float* __restrict__ mbuf, float* __restrict__ zbuf, float* __restrict__ copyp) {
    int b = blockIdx.x, t = threadIdx.x;
    __shared__ float red[256];
    const f32x4* g4 = (const f32x4*)(gene + (size_t)b * 40000);
    float mx = -3.0e38f;
    for (int i = t; i < 10000; i += 256) {
        f32x4 q = g4[i];
        mx = fmaxf(mx, fmaxf(fmaxf(q[0], q[1]), fmaxf(q[2], q[3])));
    }
    float hv = hsl[b * 256 + t];
    mx = fmaxf(mx, hv);
    if (t < 10) mx = fmaxf(mx, fmaxf(stl[b * 10 + t], acl[b * 10 + t]));
    red[t] = mx; __syncthreads();
    for (int s = 128; s > 0; s >>= 1) { if (t < s) red[t] = fmaxf(red[t], red[t + s]); __syncthreads(); }
    float m = red[0];
    __syncthreads();
    float sum = 0.f;
    for (int i = t; i < 10000; i += 256) {
        f32x4 q = g4[i];
        sum += expf(q[0]-m) + expf(q[1]-m) + expf(q[2]-m) + expf(q[3]-m);
    }
    sum += expf(hv - m);
    if (t < 10) sum += expf(stl[b * 10 + t] - m) + expf(acl[b * 10 + t] - m);
    red[t] = sum; __syncthreads();
    for (int s = 128; s > 0; s >>= 1) { if (t < s) red[t] += red[t + s]; __syncthreads(); }
    float Z = red[0];
    if (t == 0) { mbuf[b] = m; zbuf[b] = Z; }
    float wv = expf(hv - m) / Z;
    atomicAdd(copyp + (size_t)b * 40000 + hwi[b * 256 + t], wv);
}

// out = log( exp(g-m)/Z + copyp + R*exp(m~-m)/Z )
__global__ __launch_bounds__(256) void k_final(
    float* __restrict__ gene_out, const float* __restrict__ copyp,
    const float* __restrict__ R, const float* __restrict__ mbuf,
    const float* __restrict__ zbuf, const float* __restrict__ mtil) {
    int b = blockIdx.y, t = threadIdx.x;
    int v4 = blockIdx.x * 256 + t;
    if (v4 < 10000) {
        float m = mbuf[b], iz = 1.0f / zbuf[b];
        float sb = expf(mtil[b] - m) * iz;
        size_t base = (size_t)b * 10000 + v4;
        f32x4 g = ((const f32x4*)gene_out)[base];
        f32x4 c = ((const f32x4*)copyp)[base];
        f32x4 rr = ((const f32x4*)R)[base];
        f32x4 r;
#pragma unroll
        for (int j = 0; j < 4; ++j)
            r[j] = logf(expf(g[j] - m) * iz + c[j] + rr[j] * sb);
        ((f32x4*)gene_out)[base] = r;
    }
}

// ------------------------------- launcher ----------------------------------
#define OFF_QH_H  0
#define OFF_QH_S  131072
#define OFF_QH_A  262144
#define OFF_QSC   393216
#define OFF_GI    524288
#define OFF_GH    917504
#define OFF_HSC   1310720
#define OFF_STSC  1343488
#define OFF_ACSC  1344768
#define OFF_STLG  1346048
#define OFF_ACLG  1347328
#define OFF_CTR   1348608
#define OFF_DQH   1348610
#define OFF_PFX   1348736
#define OFF_NT    1348904
#define ZERO_FLOATS 1348936
#define OFF_HSL   1348992
#define OFF_M     1381760
#define OFF_Z     1381888
#define OFF_COPY  1382016
#define OFF_MTIL  6502016
#define FLOAT_TOTAL 6504704
// short region (shorts, offset from short base)
#define SO_HS     0
#define SO_SE     33554432
#define SO_AE     34865152
#define SO_Q0     36175872
#define SO_X      36306944
#define SO_HNB    36831232
#define SO_WQHT   36962304
#define SO_WQST   38010880
#define SO_WQAT   39059456
#define SO_WQSCT  40108032
#define SO_WMHT   41156608
#define SO_WMST   42205184
#define SO_WMAT   43253760
#define SO_WMSCT  44302336
#define SO_WIH    45350912
#define SO_WHH    57933824
#define SO_MSE    61079552
#define SO_MAE    62390272

extern "C" void kernel_launch(void* const* d_in, const int* in_sizes, int n_in,
                              void* d_out, int out_size, void* d_ws, size_t ws_size,
                              hipStream_t stream) {
    const float* inp     = (const float*)d_in[0];
    const float* hidden  = (const float*)d_in[1];
    const float* hs      = (const float*)d_in[2];
    const float* sprob   = (const float*)d_in[3];
    const float* se      = (const float*)d_in[4];
    const float* aprob   = (const float*)d_in[5];
    const float* ae      = (const float*)d_in[6];
    const int*   lens    = (const int*)d_in[7];
    const int*   hwi     = (const int*)d_in[8];
    const float* Wq_hist = (const float*)d_in[9];
    const float* bq_hist = (const float*)d_in[10];
    const float* Wm_hist = (const float*)d_in[11];
    const float* v_hist  = (const float*)d_in[12];
    const float* Wq_s    = (const float*)d_in[13];
    const float* bq_s    = (const float*)d_in[14];
    const float* Wm_s    = (const float*)d_in[15];
    const float* v_s     = (const float*)d_in[16];
    const float* Wq_a    = (const float*)d_in[17];
    const float* bq_a    = (const float*)d_in[18];
    const float* Wm_a    = (const float*)d_in[19];
    const float* v_a     = (const float*)d_in[20];
    const float* Wq_sc   = (const float*)d_in[21];
    const float* bq_sc   = (const float*)d_in[22];
    const float* Wm_sc   = (const float*)d_in[23];
    const float* v_sc    = (const float*)d_in[24];
    const float* W_ih    = (const float*)d_in[25];
    const float* W_hh    = (const float*)d_in[26];
    const float* b_ih    = (const float*)d_in[27];
    const float* b_hh    = (const float*)d_in[28];
    const float* W_out   = (const float*)d_in[29];
    const float* b_out   = (const float*)d_in[30];

    float* out  = (float*)d_out;
    float* w    = (float*)d_ws;
    float* hnew = out + BV;
    unsigned short* sb = (unsigned short*)(w + FLOAT_TOTAL);

    float* qh_h = w + OFF_QH_H;  float* qh_s = w + OFF_QH_S;  float* qh_a = w + OFF_QH_A;
    float* gi   = w + OFF_GI;    float* gh   = w + OFF_GH;
    float* hsc  = w + OFF_HSC;   float* stsc = w + OFF_STSC;  float* acsc = w + OFF_ACSC;
    float* stlg = w + OFF_STLG;  float* aclg = w + OFF_ACLG;
    float* hsl  = w + OFF_HSL;   float* mbuf = w + OFF_M;     float* zbuf = w + OFF_Z;
    float* copyp = w + OFF_COPY;
    float* mtil = w + OFF_MTIL;
    int*   ctr  = (int*)(w + OFF_CTR);
    int*   dqh  = (int*)(w + OFF_DQH);
    int*   pfx  = (int*)(w + OFF_PFX);
    int*   ntb  = (int*)(w + OFF_NT);

    unsigned short* hs_bf = sb + SO_HS;   unsigned short* se_bf = sb + SO_SE;
    unsigned short* ae_bf = sb + SO_AE;   unsigned short* q0_bf = sb + SO_Q0;
    unsigned short* x_bf  = sb + SO_X;    unsigned short* hnb   = sb + SO_HNB;
    unsigned short* WqhT  = sb + SO_WQHT; unsigned short* WqsT  = sb + SO_WQST;
    unsigned short* WqaT  = sb + SO_WQAT; unsigned short* WqscT = sb + SO_WQSCT;
    unsigned short* WmhT  = sb + SO_WMHT; unsigned short* WmsT  = sb + SO_WMST;
    unsigned short* WmaT  = sb + SO_WMAT; unsigned short* WmscT = sb + SO_WMSCT;
    unsigned short* WihB  = sb + SO_WIH;  unsigned short* WhhB  = sb + SO_WHH;
    unsigned short* mseh  = sb + SO_MSE;  unsigned short* maeh  = sb + SO_MAE;
    float* Rbuf = (float*)(sb + SO_WIH);  // reuses WihB/WhhB region (dead after k_gigh2)

    dim3 blk(256);

    hipMemsetAsync(w, 0, (size_t)ZERO_FLOATS * 4, stream);
    hipMemsetAsync(copyp, 0, (size_t)BV * 4, stream);

    // fused prep: transpose-cvt 8 weights + lens prefix + cvt hs/se/ae/hidden
    PrepArgs pa;
    pa.cs[0]=hs; pa.cs[1]=se; pa.cs[2]=ae; pa.cs[3]=hidden;
    pa.cd[0]=hs_bf; pa.cd[1]=se_bf; pa.cd[2]=ae_bf; pa.cd[3]=q0_bf;
    pa.pre[0]=0; pa.pre[1]=4194304; pa.pre[2]=4358144; pa.pre[3]=4521984; pa.pre[4]=4538368;
    pa.ts[0]=Wq_hist; pa.ts[1]=Wq_s; pa.ts[2]=Wq_a; pa.ts[3]=Wq_sc;
    pa.ts[4]=Wm_hist; pa.ts[5]=Wm_s; pa.ts[6]=Wm_a; pa.ts[7]=Wm_sc;
    pa.td[0]=WqhT; pa.td[1]=WqsT; pa.td[2]=WqaT; pa.td[3]=WqscT;
    pa.td[4]=WmhT; pa.td[5]=WmsT; pa.td[6]=WmaT; pa.td[7]=WmscT;
    pa.lens = lens; pa.prefix = pfx; pa.nt = ntb;
    k_prep<<<dim3(4097), blk, 0, stream>>>(pa);

    // qh + att + stac + hist (compact) + W cvt: persistent 4-phase GEMM
    BigArgs ba;
    ba.hs = hs_bf; ba.WmhT = WmhT; ba.se = se_bf; ba.ae = ae_bf;
    ba.WmsT = WmsT; ba.WmaT = WmaT; ba.WmscT = WmscT;
    ba.q0 = q0_bf; ba.Wq0T = WqhT; ba.Wq1T = WqsT; ba.Wq2T = WqaT;
    ba.Wihf = W_ih; ba.Whhf = W_hh; ba.WihB = WihB; ba.WhhB = WhhB;
    ba.bq_h = bq_hist; ba.v_h = v_hist;
    ba.bq_s = bq_s; ba.v_s = v_s;
    ba.bq_a = bq_a; ba.v_a = v_a;
    ba.qh_h = qh_h; ba.qh_s = qh_s; ba.qh_a = qh_a;
    ba.hsc = hsc; ba.stsc = stsc; ba.acsc = acsc;
    ba.mseh = mseh; ba.maeh = maeh;
    k_big<<<dim3(256), dim3(512), 0, stream>>>(ba, ctr, dqh, pfx, ntb);

    // contexts -> x (bf16)
    k_ctx<<<dim3(128), blk, 0, stream>>>(hsc, lens, pfx, hs_bf, inp, stsc, acsc, se_bf, ae_bf, x_bf);
    // GRU gates
    k_gigh2<<<dim3(24, 8, 2), blk, 0, stream>>>(x_bf, q0_bf, WihB, WhhB, gi, gh);
    // GRU elementwise + hs logits + qsc + stac logits + mtil
    k_gruhsl<<<dim3(128, 2), dim3(1024), 0, stream>>>(gi, gh, b_ih, b_hh, hidden, hnew, hnb,
                                                      hs_bf, hsl, WqscT, mseh, maeh, bq_sc, v_sc,
                                                      Wm_sc + (size_t)1024 * 1024, stlg, aclg, mtil);
    // gene logits + R (overlapped in one launch)
    k_geneR<<<dim3(313 + 5120), blk, 0, stream>>>(hnb, W_out, b_out, out, sprob, aprob,
                                                  stlg, aclg, mtil, Rbuf);
    // softmax stats + scatter
    k_smsc<<<dim3(128), blk, 0, stream>>>(out, hsl, stlg, aclg, hwi, mbuf, zbuf, copyp);
    // fused final (gene + copyp + R only)
    k_final<<<dim3(40, 128), blk, 0, stream>>>(out, copyp, Rbuf, mbuf, zbuf, mtil);

    (void)in_sizes; (void)n_in; (void)out_size; (void)ws_size;
}

// Round 10
// 549.036 us; speedup vs baseline: 1.0451x; 1.0451x over previous
//
#include <hip/hip_runtime.h>
#include <stdint.h>

typedef __attribute__((ext_vector_type(4))) float f32x4;
typedef __attribute__((ext_vector_type(2))) unsigned int u32x2;
typedef __attribute__((ext_vector_type(4))) unsigned int u32x4;
typedef __attribute__((ext_vector_type(8))) short bf16x8;

#define BV (128*40000)

__device__ __forceinline__ unsigned rne_bf16(float f) {
    unsigned x = __float_as_uint(f);
    return ((x + 0x7FFFu + ((x >> 16) & 1u)) >> 16) & 0xFFFFu;
}
__device__ __forceinline__ unsigned pack2(float a, float b) {
    return rne_bf16(a) | (rne_bf16(b) << 16);
}
__device__ __forceinline__ float bf2f(unsigned u) {
    return __uint_as_float((u & 0xFFFFu) << 16);
}
__device__ __forceinline__ float sigm(float x) { return 1.0f / (1.0f + expf(-x)); }
__device__ __forceinline__ float ftanh(float x) {
    float e = __expf(2.0f * x);
    return 1.0f - 2.0f / (e + 1.0f);
}

__device__ __forceinline__ void gload16(const void* g, void* l) {
    __builtin_amdgcn_global_load_lds(
        (const __attribute__((address_space(1))) unsigned*)g,
        (__attribute__((address_space(3))) unsigned*)l, 16, 0, 0);
}

// ---------------------------------------------------------------------------
// Persistent 256x256-tile bf16 MFMA GEMM, counted-vmcnt double-buffered
// pipeline, dynamic tile queue (exact R5 structure, measured 125us).
// Queue: 0..39 att score (cls0, tanh-reduce) | 40..79 stac pre-act (cls1,
// bf16 store) | 80.. hist compact rows (cls2, tanh-reduce, mask-skipped).
// ---------------------------------------------------------------------------
struct BigArgs {
    const unsigned short *hs, *WmhT, *se, *ae, *WmsT, *WmaT, *WmscT;
    const float *qh_h, *bq_h, *v_h;
    const float *qh_s, *bq_s, *v_s;
    const float *qh_a, *bq_a, *v_a;
    float *hsc, *stsc, *acsc;
    unsigned short *mseh, *maeh;
};

__global__ __launch_bounds__(512, 1) void k_big(
    BigArgs a, int* __restrict__ ctr, const int* __restrict__ prefix,
    const int* __restrict__ ntp) {
    __shared__ unsigned short As[2][16384];
    __shared__ unsigned short Bs[2][16384];
    __shared__ int sTile;
    __shared__ int rows_tab[256];

    const int nTiles = ntp[0], Mp = ntp[1];
    const int t = threadIdx.x, lane = t & 63, wv = t >> 6;
    const int l16 = lane & 15, lq = lane >> 4;
    const int wm = wv >> 2, wn = wv & 3;
    const int srowL = t >> 3;
    const int gccA = ((t & 7) ^ (srowL & 7)) << 3;
    const int sw = l16 & 7;
    const int c0 = ((lq ^ sw) << 3);
    const int A0 = (wm << 13) + (l16 << 6);
    const int B0 = ((wn >> 1) << 13) + ((((wn & 1) << 6) + l16) << 6);

#define STAGE(kt, d)                                                          \
    {                                                                         \
        _Pragma("unroll")                                                     \
        for (int q_ = 0; q_ < 4; ++q_) {                                      \
            int lo_ = (q_ << 12) + (wv << 9);                                 \
            gload16(gAr[q_] + (kt) * 64, &As[d][lo_]);                        \
            gload16(gB + (size_t)(q_ << 16) + (kt) * 64, &Bs[d][lo_]);        \
        }                                                                     \
    }

    for (;;) {
        __syncthreads();
        if (t == 0) sTile = atomicAdd(ctr, 1);
        __syncthreads();
        const int wg = sTile;
        if (wg >= nTiles) return;

        const unsigned short *Abase, *Bt;
        const float *rb = nullptr, *cb = nullptr, *vv = nullptr;
        float* out = nullptr;
        unsigned short* outh = nullptr;
        int m0, n0, vrows, cls;
        if (wg < 40) {
            cls = 0;
            int op = wg / 20, r = wg - op * 20;
            int mt = r >> 2, nt2 = r & 3;
            if (op == 0) { Abase = a.se; Bt = a.WmsT; rb = a.qh_s; cb = a.bq_s; vv = a.v_s; out = a.stsc; }
            else         { Abase = a.ae; Bt = a.WmaT; rb = a.qh_a; cb = a.bq_a; vv = a.v_a; out = a.acsc; }
            m0 = mt << 8; n0 = nt2 << 8; vrows = 256;
        } else if (wg < 80) {
            cls = 1;
            int r = wg - 40;
            int op = r / 20; r -= op * 20;
            int mt = r >> 2, nt2 = r & 3;
            Abase = op ? a.ae : a.se; Bt = a.WmscT;
            outh = op ? a.maeh : a.mseh;
            m0 = mt << 8; n0 = nt2 << 8; vrows = 256;
        } else {
            cls = 2;
            int h = wg - 80;
            int m = h >> 2, n = h & 3;
            Abase = a.hs; Bt = a.WmhT; rb = a.qh_h; cb = a.bq_h; vv = a.v_h; out = a.hsc;
            m0 = m << 8; n0 = n << 8;
            vrows = Mp - m0; if (vrows > 256) vrows = 256;
        }

        if (t < 256) {
            int rid;
            if (cls != 2) {
                rid = m0 + t;
            } else {
                int g = m0 + t;
                if (g < Mp) {
                    int lo = 0, hi = 128;
                    while (hi - lo > 1) {
                        int mid = (lo + hi) >> 1;
                        if (prefix[mid] <= g) lo = mid; else hi = mid;
                    }
                    rid = (lo << 8) + (g - prefix[lo]);
                } else {
                    rid = 0;
                }
            }
            rows_tab[t] = rid;
        }
        __syncthreads();

        const unsigned short* gAr[4];
#pragma unroll
        for (int q = 0; q < 4; ++q)
            gAr[q] = Abase + ((size_t)rows_tab[srowL + (q << 6)] << 10) + gccA;
        const unsigned short* gB = Bt + (size_t)(n0 + srowL) * 1024 + gccA;

        f32x4 acc[8][4];
#pragma unroll
        for (int i = 0; i < 8; ++i)
#pragma unroll
            for (int j = 0; j < 4; ++j) acc[i][j] = (f32x4){0.f, 0.f, 0.f, 0.f};

        STAGE(0, 0);
        for (int kt = 0; kt < 16; ++kt) {
            int cur = kt & 1;
            if (kt < 15) {
                STAGE(kt + 1, cur ^ 1);
                asm volatile("s_waitcnt vmcnt(8)" ::: "memory");
            } else {
                asm volatile("s_waitcnt vmcnt(0)" ::: "memory");
            }
            __builtin_amdgcn_s_barrier();
            __builtin_amdgcn_sched_barrier(0);

            const unsigned short* ab = As[cur];
            const unsigned short* bb = Bs[cur];
            if (vrows > (wm << 7)) {
                bf16x8 bf0[4], bf1[4];
#pragma unroll
                for (int nf = 0; nf < 4; ++nf) {
                    bf0[nf] = *(const bf16x8*)(bb + B0 + (nf << 10) + c0);
                    bf1[nf] = *(const bf16x8*)(bb + B0 + (nf << 10) + (c0 ^ 32));
                }
#pragma unroll
                for (int mf = 0; mf < 8; ++mf) {
                    if ((wm << 7) + (mf << 4) < vrows) {
                        bf16x8 a0 = *(const bf16x8*)(ab + A0 + (mf << 10) + c0);
                        bf16x8 a1 = *(const bf16x8*)(ab + A0 + (mf << 10) + (c0 ^ 32));
#pragma unroll
                        for (int nf = 0; nf < 4; ++nf)
                            acc[mf][nf] = __builtin_amdgcn_mfma_f32_16x16x32_bf16(a0, bf0[nf], acc[mf][nf], 0, 0, 0);
#pragma unroll
                        for (int nf = 0; nf < 4; ++nf)
                            acc[mf][nf] = __builtin_amdgcn_mfma_f32_16x16x32_bf16(a1, bf1[nf], acc[mf][nf], 0, 0, 0);
                    }
                }
            }
            __builtin_amdgcn_sched_barrier(0);
            __builtin_amdgcn_s_barrier();
        }

        if (cls == 1) {
            // bf16 store of the copy-scorer pre-activation
            int gcs4[4];
#pragma unroll
            for (int nf = 0; nf < 4; ++nf) gcs4[nf] = n0 + (wn << 6) + (nf << 4) + l16;
#pragma unroll
            for (int mf = 0; mf < 8; ++mf) {
#pragma unroll
                for (int r = 0; r < 4; ++r) {
                    int grow = m0 + (wm << 7) + (mf << 4) + (lq << 2) + r;
#pragma unroll
                    for (int nf = 0; nf < 4; ++nf)
                        outh[(size_t)grow * 1024 + gcs4[nf]] = (unsigned short)rne_bf16(acc[mf][nf][r]);
                }
            }
        } else {
            float cbv[4], vvv[4];
            int gcs[4];
#pragma unroll
            for (int nf = 0; nf < 4; ++nf) {
                int gc = n0 + (wn << 6) + (nf << 4) + l16;
                gcs[nf] = gc; cbv[nf] = cb[gc]; vvv[nf] = vv[gc];
            }
#pragma unroll
            for (int mf = 0; mf < 8; ++mf) {
                int rloc = (wm << 7) + (mf << 4);
                if (rloc < vrows) {
#pragma unroll
                    for (int r = 0; r < 4; ++r) {
                        int lrow = rloc + (lq << 2) + r;
                        if (lrow >= vrows) continue;
                        int gr = m0 + lrow;
                        int bidx = (cls == 2) ? (rows_tab[lrow] >> 8) : (gr / 10);
                        const float* rbp = rb + ((size_t)bidx << 10);
                        float s = 0.f;
#pragma unroll
                        for (int nf = 0; nf < 4; ++nf) {
                            float x = acc[mf][nf][r] + rbp[gcs[nf]] + cbv[nf];
                            s += ftanh(x) * vvv[nf];
                        }
#pragma unroll
                        for (int m2 = 1; m2 < 16; m2 <<= 1) s += __shfl_xor(s, m2, 64);
                        if (l16 == 0) atomicAdd(&out[gr], s);
                    }
                }
            }
        }
    }
#undef STAGE
}

// ---------------------------------------------------------------------------
// m97-style 128x128 bf16 MFMA GEMM, split-K atomic. A bf16 gload_lds; B bf16.
// ---------------------------------------------------------------------------
__device__ __forceinline__ void mgemm2(
    const unsigned short* __restrict__ A, const unsigned short* __restrict__ Bt,
    float* __restrict__ out,
    int m0, int n0, int kb, int ke, int ldk, int ldc)
{
    __shared__ unsigned short As[2][4096];
    __shared__ unsigned short Bs[2][4096];
    const int t = threadIdx.x, lane = t & 63, wv = t >> 6;
    const int l16 = lane & 15, lq = lane >> 4;
    const int wm = wv >> 1, wn = wv & 1;

    const int srow = lane >> 2, scol = (lane & 3) << 3;
    const unsigned short* gA0 = A + (size_t)(m0 + (wv << 4) + srow) * ldk + kb + scol;
    const unsigned short* gA1 = gA0 + (size_t)64 * ldk;
    const unsigned short* gB0 = Bt + (size_t)(n0 + (wv << 4) + srow) * ldk + kb + scol;
    const unsigned short* gB1 = gB0 + (size_t)64 * ldk;
    unsigned short* lA0 = &As[0][wv << 9];
    unsigned short* lA1 = &As[0][(wv + 4) << 9];
    unsigned short* lB0 = &Bs[0][wv << 9];
    unsigned short* lB1 = &Bs[0][(wv + 4) << 9];

    f32x4 acc[4][4];
#pragma unroll
    for (int i = 0; i < 4; ++i)
#pragma unroll
        for (int j = 0; j < 4; ++j) acc[i][j] = (f32x4){0.f, 0.f, 0.f, 0.f};

    const int NS = (ke - kb) >> 5;
    gload16(gA0, lA0); gload16(gA1, lA1);
    gload16(gB0, lB0); gload16(gB1, lB1);

    for (int s = 0; s < NS; ++s) {
        __syncthreads();
        if (s + 1 < NS) {
            const int nb = (s + 1) & 1, ko = (s + 1) << 5;
            gload16(gA0 + ko, lA0 + (nb << 12)); gload16(gA1 + ko, lA1 + (nb << 12));
            gload16(gB0 + ko, lB0 + (nb << 12)); gload16(gB1 + ko, lB1 + (nb << 12));
        }
        const unsigned short* ab = As[s & 1];
        const unsigned short* bb = Bs[s & 1];
        bf16x8 af[4], bfv[4];
#pragma unroll
        for (int i = 0; i < 4; ++i)
            af[i] = *(const bf16x8*)(ab + (((wm << 6) + (i << 4) + l16) << 5) + (lq << 3));
#pragma unroll
        for (int i = 0; i < 4; ++i)
            bfv[i] = *(const bf16x8*)(bb + (((wn << 6) + (i << 4) + l16) << 5) + (lq << 3));
#pragma unroll
        for (int mf = 0; mf < 4; ++mf)
#pragma unroll
            for (int nf = 0; nf < 4; ++nf)
                acc[mf][nf] = __builtin_amdgcn_mfma_f32_16x16x32_bf16(af[mf], bfv[nf], acc[mf][nf], 0, 0, 0);
    }

#pragma unroll
    for (int mf = 0; mf < 4; ++mf) {
        int gr0 = m0 + (wm << 6) + (mf << 4) + (lq << 2);
#pragma unroll
        for (int nf = 0; nf < 4; ++nf) {
            int gc = n0 + (wn << 6) + (nf << 4) + l16;
#pragma unroll
            for (int r = 0; r < 4; ++r)
                atomicAdd(&out[(size_t)(gr0 + r) * ldc + gc], acc[mf][nf][r]);
        }
    }
}

// Same, but B is f32 N x K row-major (reg-stage cvt; coalesced along K).
__device__ __forceinline__ void mgemm2f(
    const unsigned short* __restrict__ A, const float* __restrict__ Bf,
    float* __restrict__ out,
    int m0, int n0, int kb, int ke, int ldkA, int ldkB, int ldc)
{
    __shared__ unsigned short As[2][4096];
    __shared__ unsigned short Bs[2][4096];
    const int t = threadIdx.x, lane = t & 63, wv = t >> 6;
    const int l16 = lane & 15, lq = lane >> 4;
    const int wm = wv >> 1, wn = wv & 1;

    const int srow = lane >> 2, scol = (lane & 3) << 3;
    const unsigned short* gA0 = A + (size_t)(m0 + (wv << 4) + srow) * ldkA + kb + scol;
    const unsigned short* gA1 = gA0 + (size_t)64 * ldkA;
    unsigned short* lA0 = &As[0][wv << 9];
    unsigned short* lA1 = &As[0][(wv + 4) << 9];

    const int bn = t >> 1, kh = (t & 1) << 4;
    const float* gB = Bf + (size_t)(n0 + bn) * ldkB + kb + kh;

    f32x4 acc[4][4];
#pragma unroll
    for (int i = 0; i < 4; ++i)
#pragma unroll
        for (int j = 0; j < 4; ++j) acc[i][j] = (f32x4){0.f, 0.f, 0.f, 0.f};

    auto stageB = [&](int buf, int ko) {
        const float* s = gB + ko;
        f32x4 f0 = *(const f32x4*)(s);
        f32x4 f1 = *(const f32x4*)(s + 4);
        f32x4 f2 = *(const f32x4*)(s + 8);
        f32x4 f3 = *(const f32x4*)(s + 12);
        u32x4* d = (u32x4*)&Bs[buf][bn * 32 + kh];
        d[0] = (u32x4){pack2(f0[0],f0[1]), pack2(f0[2],f0[3]), pack2(f1[0],f1[1]), pack2(f1[2],f1[3])};
        d[1] = (u32x4){pack2(f2[0],f2[1]), pack2(f2[2],f2[3]), pack2(f3[0],f3[1]), pack2(f3[2],f3[3])};
    };

    const int NS = (ke - kb) >> 5;
    gload16(gA0, lA0); gload16(gA1, lA1); stageB(0, 0);
    for (int s = 0; s < NS; ++s) {
        __syncthreads();
        if (s + 1 < NS) {
            const int nb = (s + 1) & 1, ko = (s + 1) << 5;
            gload16(gA0 + ko, lA0 + (nb << 12)); gload16(gA1 + ko, lA1 + (nb << 12));
            stageB(nb, ko);
        }
        const unsigned short* ab = As[s & 1];
        const unsigned short* bb = Bs[s & 1];
        bf16x8 af[4], bfv[4];
#pragma unroll
        for (int i = 0; i < 4; ++i)
            af[i] = *(const bf16x8*)(ab + (((wm << 6) + (i << 4) + l16) << 5) + (lq << 3));
#pragma unroll
        for (int i = 0; i < 4; ++i)
            bfv[i] = *(const bf16x8*)(bb + (((wn << 6) + (i << 4) + l16) << 5) + (lq << 3));
#pragma unroll
        for (int mf = 0; mf < 4; ++mf)
#pragma unroll
            for (int nf = 0; nf < 4; ++nf)
                acc[mf][nf] = __builtin_amdgcn_mfma_f32_16x16x32_bf16(af[mf], bfv[nf], acc[mf][nf], 0, 0, 0);
    }

#pragma unroll
    for (int mf = 0; mf < 4; ++mf) {
        int gr0 = m0 + (wm << 6) + (mf << 4) + (lq << 2);
#pragma unroll
        for (int nf = 0; nf < 4; ++nf) {
            int gc = n0 + (wn << 6) + (nf << 4) + l16;
#pragma unroll
            for (int r = 0; r < 4; ++r)
                atomicAdd(&out[(size_t)(gr0 + r) * ldc + gc], acc[mf][nf][r]);
        }
    }
}

// gene logits: A = hnew bf16 (gload_lds), B = W_out f32 KxN (reg-stage cvt)
__device__ __forceinline__ void gene_body(
    const unsigned short* __restrict__ hnb, const float* __restrict__ Wout,
    const float* __restrict__ b_out, float* __restrict__ out, int n0)
{
    __shared__ unsigned short As[2][4096];
    __shared__ unsigned short Bs[2][4096];
    const int t = threadIdx.x, lane = t & 63, wv = t >> 6;
    const int l16 = lane & 15, lq = lane >> 4;
    const int wm = wv >> 1, wn = wv & 1;

    const int srow = lane >> 2, scol = (lane & 3) << 3;
    const unsigned short* gA0 = hnb + (size_t)((wv << 4) + srow) * 1024 + scol;
    const unsigned short* gA1 = gA0 + (size_t)64 * 1024;
    unsigned short* lA0 = &As[0][wv << 9];
    unsigned short* lA1 = &As[0][(wv + 4) << 9];

    const int bn = t & 127, kh = t >> 7;
    const bool ok = (n0 + bn) < 40000;
    const float* gB = Wout + (size_t)(kh * 16) * 40000 + (n0 + bn);

    f32x4 acc[4][4];
#pragma unroll
    for (int i = 0; i < 4; ++i)
#pragma unroll
        for (int j = 0; j < 4; ++j) acc[i][j] = (f32x4){0.f, 0.f, 0.f, 0.f};

    auto stageB = [&](int buf, int ko) {
        const float* src = gB + (size_t)ko * 40000;
        float f[16];
#pragma unroll
        for (int j = 0; j < 16; ++j) f[j] = ok ? src[(size_t)j * 40000] : 0.0f;
        u32x4* d = (u32x4*)&Bs[buf][bn * 32 + kh * 16];
        d[0] = (u32x4){pack2(f[0],f[1]), pack2(f[2],f[3]), pack2(f[4],f[5]), pack2(f[6],f[7])};
        d[1] = (u32x4){pack2(f[8],f[9]), pack2(f[10],f[11]), pack2(f[12],f[13]), pack2(f[14],f[15])};
    };

    gload16(gA0, lA0); gload16(gA1, lA1); stageB(0, 0);
    for (int s = 0; s < 32; ++s) {
        __syncthreads();
        if (s + 1 < 32) {
            const int nb = (s + 1) & 1, ko = (s + 1) << 5;
            gload16(gA0 + ko, lA0 + (nb << 12)); gload16(gA1 + ko, lA1 + (nb << 12));
            stageB(nb, ko);
        }
        const unsigned short* ab = As[s & 1];
        const unsigned short* bb = Bs[s & 1];
        bf16x8 af[4], bfv[4];
#pragma unroll
        for (int i = 0; i < 4; ++i)
            af[i] = *(const bf16x8*)(ab + (((wm << 6) + (i << 4) + l16) << 5) + (lq << 3));
#pragma unroll
        for (int i = 0; i < 4; ++i)
            bfv[i] = *(const bf16x8*)(bb + (((wn << 6) + (i << 4) + l16) << 5) + (lq << 3));
#pragma unroll
        for (int mf = 0; mf < 4; ++mf)
#pragma unroll
            for (int nf = 0; nf < 4; ++nf)
                acc[mf][nf] = __builtin_amdgcn_mfma_f32_16x16x32_bf16(af[mf], bfv[nf], acc[mf][nf], 0, 0, 0);
    }
#pragma unroll
    for (int mf = 0; mf < 4; ++mf) {
        int gr0 = (wm << 6) + (mf << 4) + (lq << 2);
#pragma unroll
        for (int nf = 0; nf < 4; ++nf) {
            int gc = n0 + (wn << 6) + (nf << 4) + l16;
            if (gc < 40000) {
                float bo = b_out[gc];
#pragma unroll
                for (int r = 0; r < 4; ++r)
                    out[(size_t)(gr0 + r) * 40000 + gc] = acc[mf][nf][r] + bo;
            }
        }
    }
}

// ------------------------------ GEMM wrappers ------------------------------
__global__ __launch_bounds__(256) void k_qh4(
    const unsigned short* q0, const unsigned short* W0, const unsigned short* W1,
    const unsigned short* W2, float* o0, float* o1, float* o2) {
    const unsigned short* W = W0; float* o = o0;
    if (blockIdx.z == 1) { W = W1; o = o1; }
    if (blockIdx.z == 2) { W = W2; o = o2; }
    int kb = blockIdx.y << 8;
    mgemm2(q0, W, o, 0, blockIdx.x * 128, kb, kb + 256, 1024, 1024);
}

__global__ __launch_bounds__(256) void k_gigh2(
    const unsigned short* xb, const unsigned short* q0,
    const float* Wih, const float* Whh, float* gi, float* gh) {
    if (blockIdx.z == 0) {
        int kb = blockIdx.y << 9;
        mgemm2f(xb, Wih, gi, 0, blockIdx.x * 128, kb, kb + 512, 4096, 4096, 3072);
    } else {
        if (blockIdx.y >= 2) return;
        int kb = blockIdx.y << 9;
        mgemm2f(q0, Whh, gh, 0, blockIdx.x * 128, kb, kb + 512, 1024, 1024, 3072);
    }
}

// qsc (16 blocks, split-K 2) + gene logits (313 blocks) in one launch
__global__ __launch_bounds__(256) void k_qsc_gene(
    const unsigned short* hnb, const unsigned short* WqscT, float* qsc,
    const float* Wout, const float* b_out, float* out) {
    int id = blockIdx.x;
    if (id < 16) {
        int x = id & 7, kb = (id >> 3) << 9;
        mgemm2(hnb, WqscT, qsc, 0, x * 128, kb, kb + 512, 1024, 1024);
    } else {
        gene_body(hnb, Wout, b_out, out, (id - 16) << 7);
    }
}

// --------------------------- prep kernel ------------------------------------
struct PrepArgs {
    const float* cs[4]; unsigned short* cd[4]; int pre[5];
    const float* ts[8]; unsigned short* td[8];
    const int* lens; int* prefix; int* nt;
};
__global__ __launch_bounds__(256) void k_prep(PrepArgs a) {
    int bid = blockIdx.x, t = threadIdx.x;
    if (bid < 2048) {
        __shared__ float tile[64][65];
        int z = bid >> 8, rem = bid & 255, y = rem >> 4, x = rem & 15;
        const float* in = a.ts[z];
        unsigned short* ot = a.td[z];
        int k0 = y << 6, n0 = x << 6;
        int tr = t >> 6, tc = t & 63;
#pragma unroll
        for (int i = 0; i < 16; ++i) {
            int r = (i << 2) + tr;
            tile[r][tc] = in[(size_t)(k0 + r) * 1024 + n0 + tc];
        }
        __syncthreads();
#pragma unroll
        for (int i = 0; i < 16; ++i) {
            int r = (i << 2) + tr;
            ot[(size_t)(n0 + r) * 1024 + k0 + tc] = (unsigned short)rne_bf16(tile[tc][r]);
        }
    } else if (bid == 2048) {
        __shared__ int sc[128];
        if (t < 128) sc[t] = a.lens[t];
        __syncthreads();
        for (int off = 1; off < 128; off <<= 1) {
            int x = (t >= off && t < 128) ? sc[t - off] : 0;
            __syncthreads();
            if (t < 128) sc[t] += x;
            __syncthreads();
        }
        if (t == 0) a.prefix[0] = 0;
        if (t < 128) a.prefix[t + 1] = sc[t];
        if (t == 127) {
            int Mp = sc[127];
            a.nt[0] = 80 + (((Mp + 255) >> 8) << 2);
            a.nt[1] = Mp;
        }
    } else {
        int total = a.pre[4];
        for (int i = (bid - 2049) * 256 + t; i < total; i += 2048 * 256) {
            int seg = 0;
            while (i >= a.pre[seg + 1]) ++seg;
            int loc = i - a.pre[seg];
            const f32x4* s4 = (const f32x4*)a.cs[seg] + (size_t)loc * 2;
            f32x4 q0 = s4[0], q1 = s4[1];
            ((u32x4*)a.cd[seg])[loc] =
                (u32x4){pack2(q0[0],q0[1]), pack2(q0[2],q0[3]), pack2(q1[0],q1[1]), pack2(q1[2],q1[3])};
        }
    }
}

// --------------------------- non-GEMM kernels ------------------------------
__device__ __forceinline__ void softmax10(const float* src, float* dst) {
    float m = src[0];
    for (int i = 1; i < 10; ++i) m = fmaxf(m, src[i]);
    float z = 0.f, e[10];
    for (int i = 0; i < 10; ++i) { e[i] = expf(src[i] - m); z += e[i]; }
    float iz = 1.0f / z;
    for (int i = 0; i < 10; ++i) dst[i] = e[i] * iz;
}

__global__ __launch_bounds__(256) void k_ctx(
    const float* __restrict__ scores, const int* __restrict__ lens,
    const int* __restrict__ prefix,
    const unsigned short* __restrict__ hs,
    const float* __restrict__ inp, const float* __restrict__ st_sc, const float* __restrict__ ac_sc,
    const unsigned short* __restrict__ se, const unsigned short* __restrict__ ae,
    unsigned short* __restrict__ xb) {
    int b = blockIdx.x, t = threadIdx.x;
    __shared__ float w[256];
    __shared__ float red[256];
    __shared__ float sw[10], aw[10];
    int len = lens[b];
    int base = prefix[b];
    bool valid = t < len;
    float s = valid ? scores[base + t] : -3.0e38f;
    red[t] = s;
    __syncthreads();
    for (int st = 128; st > 0; st >>= 1) { if (t < st) red[t] = fmaxf(red[t], red[t + st]); __syncthreads(); }
    float m = red[0];
    __syncthreads();
    float e = valid ? expf(s - m) : 0.0f;
    red[t] = e;
    __syncthreads();
    for (int st = 128; st > 0; st >>= 1) { if (t < st) red[t] += red[t + st]; __syncthreads(); }
    float Z = red[0];
    __syncthreads();
    w[t] = e / Z;
    if (t == 0) softmax10(st_sc + b * 10, sw);
    if (t == 64) softmax10(ac_sc + b * 10, aw);
    f32x4 iv = ((const f32x4*)(inp + (size_t)b * 1024))[t];
    *((u32x2*)(xb + (size_t)b * 4096) + t) = (u32x2){pack2(iv[0], iv[1]), pack2(iv[2], iv[3])};
    __syncthreads();
    float a0 = 0.f, a1 = 0.f, a2 = 0.f, a3 = 0.f;
    for (int l = 0; l < 256; ++l) {
        float wl = w[l];
        if (wl == 0.0f) continue;
        u32x2 u = *((const u32x2*)(hs + ((size_t)b * 256 + l) * 1024) + t);
        a0 += wl * bf2f(u[0]); a1 += wl * bf2f(u[0] >> 16);
        a2 += wl * bf2f(u[1]); a3 += wl * bf2f(u[1] >> 16);
    }
    *((u32x2*)(xb + (size_t)b * 4096 + 1024) + t) = (u32x2){pack2(a0, a1), pack2(a2, a3)};
    float cs0=0,cs1=0,cs2=0,cs3=0, ca0=0,ca1=0,ca2=0,ca3=0;
#pragma unroll
    for (int q = 0; q < 10; ++q) {
        u32x2 us = *((const u32x2*)(se + ((size_t)b * 10 + q) * 1024) + t);
        u32x2 ua = *((const u32x2*)(ae + ((size_t)b * 10 + q) * 1024) + t);
        float ws = sw[q], wa = aw[q];
        cs0 += ws * bf2f(us[0]); cs1 += ws * bf2f(us[0] >> 16);
        cs2 += ws * bf2f(us[1]); cs3 += ws * bf2f(us[1] >> 16);
        ca0 += wa * bf2f(ua[0]); ca1 += wa * bf2f(ua[0] >> 16);
        ca2 += wa * bf2f(ua[1]); ca3 += wa * bf2f(ua[1] >> 16);
    }
    *((u32x2*)(xb + (size_t)b * 4096 + 2048) + t) = (u32x2){pack2(cs0, cs1), pack2(cs2, cs3)};
    *((u32x2*)(xb + (size_t)b * 4096 + 3072) + t) = (u32x2){pack2(ca0, ca1), pack2(ca2, ca3)};
}

// GRU elementwise + hs_logits fused; blocks (b, yhalf); y=0 writes hnew
__global__ __launch_bounds__(1024) void k_gruhsl(
    const float* __restrict__ gi, const float* __restrict__ gh,
    const float* __restrict__ b_ih, const float* __restrict__ b_hh,
    const float* __restrict__ h0, float* __restrict__ hnew,
    unsigned short* __restrict__ hnb,
    const unsigned short* __restrict__ hs, float* __restrict__ hsl) {
    int b = blockIdx.x, y = blockIdx.y, j = threadIdx.x;
    size_t i = (size_t)b * 1024 + j;
    const float* gib = gi + (size_t)b * 3072;
    const float* ghb = gh + (size_t)b * 3072;
    float r = sigm(gib[j] + b_ih[j] + ghb[j] + b_hh[j]);
    float z = sigm(gib[1024 + j] + b_ih[1024 + j] + ghb[1024 + j] + b_hh[1024 + j]);
    float hn = ghb[2048 + j] + b_hh[2048 + j];
    float n = tanhf(gib[2048 + j] + b_ih[2048 + j] + r * hn);
    float h = (1.0f - z) * n + z * h0[i];
    if (y == 0) {
        hnew[i] = h;
        hnb[i] = (unsigned short)rne_bf16(h);
    }
    __shared__ float hsm[1024];
    hsm[j] = h;
    __syncthreads();
    int wave = j >> 6, lane = j & 63;
    float hr[16];
#pragma unroll
    for (int k = 0; k < 16; ++k) hr[k] = hsm[lane * 16 + k];
    for (int l = (y << 7) + wave; l < (y << 7) + 128; l += 16) {
        const u32x4* row = (const u32x4*)(hs + ((size_t)b * 256 + l) * 1024);
        u32x4 u0 = row[lane * 2], u1 = row[lane * 2 + 1];
        float s = hr[0]*bf2f(u0[0]) + hr[1]*bf2f(u0[0]>>16) + hr[2]*bf2f(u0[1]) + hr[3]*bf2f(u0[1]>>16)
                + hr[4]*bf2f(u0[2]) + hr[5]*bf2f(u0[2]>>16) + hr[6]*bf2f(u0[3]) + hr[7]*bf2f(u0[3]>>16)
                + hr[8]*bf2f(u1[0]) + hr[9]*bf2f(u1[0]>>16) + hr[10]*bf2f(u1[1]) + hr[11]*bf2f(u1[1]>>16)
                + hr[12]*bf2f(u1[2]) + hr[13]*bf2f(u1[2]>>16) + hr[14]*bf2f(u1[3]) + hr[15]*bf2f(u1[3]>>16);
#pragma unroll
        for (int msk = 1; msk < 64; msk <<= 1) s += __shfl_xor(s, msk, 64);
        if (lane == 0) hsl[b * 256 + l] = s;
    }
}

// stac epilogue: stlg/aclg from mseh/maeh + qsc (parallel, 4 waves x 5 rows)
__global__ __launch_bounds__(256) void k_stacep(
    const unsigned short* __restrict__ mseh, const unsigned short* __restrict__ maeh,
    const float* __restrict__ qsc, const float* __restrict__ bq_sc,
    const float* __restrict__ v_sc, const float* __restrict__ tagrow,
    float* __restrict__ stlg, float* __restrict__ aclg) {
    int b = blockIdx.x, t = threadIdx.x, w = t >> 6, lane = t & 63;
    __shared__ float res[20];
    const float* qb = qsc + (size_t)b * 1024;
    for (int r = w; r < 20; r += 4) {
        bool ac = r >= 10;
        int s = ac ? r - 10 : r;
        const unsigned short* mm = (ac ? maeh : mseh) + ((size_t)b * 10 + s) * 1024;
        float acc = 0.f;
#pragma unroll
        for (int j2 = 0; j2 < 16; ++j2) {
            int c = lane + (j2 << 6);
            float x = bf2f(mm[c]) + qb[c] + bq_sc[c];
            if (ac) x += tagrow[c];
            acc += ftanh(x) * v_sc[c];
        }
#pragma unroll
        for (int m2 = 1; m2 < 64; m2 <<= 1) acc += __shfl_xor(acc, m2, 64);
        if (lane == 0) res[r] = acc;
    }
    __syncthreads();
    if (t < 10) stlg[b * 10 + t] = res[t];
    if (t >= 64 && t < 74) aclg[b * 10 + (t - 64)] = res[10 + (t - 64)];
}

// softmax stats over concat + copy_p scatter; one block per b
__global__ __launch_bounds__(256) void k_smsc(
    const float* __restrict__ gene, const float* __restrict__ hsl,
    const float* __restrict__ stl, const float* __restrict__ acl,
    const int* __restrict__ hwi,
    float* __restrict__ mbuf, float* __restrict__ zbuf, float* __restrict__ copyp) {
    int b = blockIdx.x, t = threadIdx.x;
    __shared__ float red[256];
    const f32x4* g4 = (const f32x4*)(gene + (size_t)b * 40000);
    float mx = -3.0e38f;
    for (int i = t; i < 10000; i += 256) {
        f32x4 q = g4[i];
        mx = fmaxf(mx, fmaxf(fmaxf(q[0], q[1]), fmaxf(q[2], q[3])));
    }
    float hv = hsl[b * 256 + t];
    mx = fmaxf(mx, hv);
    if (t < 10) mx = fmaxf(mx, fmaxf(stl[b * 10 + t], acl[b * 10 + t]));
    red[t] = mx; __syncthreads();
    for (int s = 128; s > 0; s >>= 1) { if (t < s) red[t] = fmaxf(red[t], red[t + s]); __syncthreads(); }
    float m = red[0];
    __syncthreads();
    float sum = 0.f;
    for (int i = t; i < 10000; i += 256) {
        f32x4 q = g4[i];
        sum += expf(q[0]-m) + expf(q[1]-m) + expf(q[2]-m) + expf(q[3]-m);
    }
    sum += expf(hv - m);
    if (t < 10) sum += expf(stl[b * 10 + t] - m) + expf(acl[b * 10 + t] - m);
    red[t] = sum; __syncthreads();
    for (int s = 128; s > 0; s >>= 1) { if (t < s) red[t] += red[t + s]; __syncthreads(); }
    float Z = red[0];
    if (t == 0) { mbuf[b] = m; zbuf[b] = Z; }
    float wv = expf(hv - m) / Z;
    atomicAdd(copyp + (size_t)b * 40000 + hwi[b * 256 + t], wv);
}

__global__ __launch_bounds__(256) void k_final(
    float* __restrict__ gene_out, const float* __restrict__ copyp,
    const float* __restrict__ sprob, const float* __restrict__ aprob,
    const float* __restrict__ stl, const float* __restrict__ acl,
    const float* __restrict__ mbuf, const float* __restrict__ zbuf) {
    int b = blockIdx.y, t = threadIdx.x;
    __shared__ float sw[10], aw[10];
    float m = mbuf[b], iz = 1.0f / zbuf[b];
    if (t < 10) sw[t] = expf(stl[b * 10 + t] - m) * iz;
    if (t >= 64 && t < 74) aw[t - 64] = expf(acl[b * 10 + (t - 64)] - m) * iz;
    __syncthreads();
    int v4 = blockIdx.x * 256 + t;
    if (v4 < 10000) {
        size_t base = (size_t)b * 10000 + v4;
        f32x4 g = ((const f32x4*)gene_out)[base];
        f32x4 c = ((const f32x4*)copyp)[base];
        f32x4 acc;
#pragma unroll
        for (int j = 0; j < 4; ++j) acc[j] = expf(g[j] - m) * iz + c[j];
#pragma unroll
        for (int s = 0; s < 10; ++s) {
            f32x4 pv = ((const f32x4*)sprob)[((size_t)b * 10 + s) * 10000 + v4];
            f32x4 av = ((const f32x4*)aprob)[((size_t)b * 10 + s) * 10000 + v4];
            float ws = sw[s], wa = aw[s];
#pragma unroll
            for (int j = 0; j < 4; ++j) acc[j] += ws * pv[j] + wa * av[j];
        }
        f32x4 r;
#pragma unroll
        for (int j = 0; j < 4; ++j) r[j] = logf(acc[j]);
        ((f32x4*)gene_out)[base] = r;
    }
}

// ------------------------------- launcher ----------------------------------
#define OFF_QH_H  0
#define OFF_QH_S  131072
#define OFF_QH_A  262144
#define OFF_QSC   393216
#define OFF_GI    524288
#define OFF_GH    917504
#define OFF_HSC   1310720
#define OFF_STSC  1343488
#define OFF_ACSC  1344768
#define OFF_STLG  1346048
#define OFF_ACLG  1347328
#define OFF_CTR   1348608
#define OFF_PFX   1348736
#define OFF_NT    1348904
#define ZERO_FLOATS 1348936
#define OFF_HSL   1348992
#define OFF_M     1381760
#define OFF_Z     1381888
#define OFF_COPY  1382016
#define FLOAT_TOTAL 6502016
// short region (shorts, offset from short base)
#define SO_HS     0
#define SO_SE     33554432
#define SO_AE     34865152
#define SO_Q0     36175872
#define SO_X      36306944
#define SO_HNB    36831232
#define SO_WQHT   36962304
#define SO_WQST   38010880
#define SO_WQAT   39059456
#define SO_WQSCT  40108032
#define SO_WMHT   41156608
#define SO_WMST   42205184
#define SO_WMAT   43253760
#define SO_WMSCT  44302336
#define SO_MSE    45350912
#define SO_MAE    46661632

extern "C" void kernel_launch(void* const* d_in, const int* in_sizes, int n_in,
                              void* d_out, int out_size, void* d_ws, size_t ws_size,
                              hipStream_t stream) {
    const float* inp     = (const float*)d_in[0];
    const float* hidden  = (const float*)d_in[1];
    const float* hs      = (const float*)d_in[2];
    const float* sprob   = (const float*)d_in[3];
    const float* se      = (const float*)d_in[4];
    const float* aprob   = (const float*)d_in[5];
    const float* ae      = (const float*)d_in[6];
    const int*   lens    = (const int*)d_in[7];
    const int*   hwi     = (const int*)d_in[8];
    const float* Wq_hist = (const float*)d_in[9];
    const float* bq_hist = (const float*)d_in[10];
    const float* Wm_hist = (const float*)d_in[11];
    const float* v_hist  = (const float*)d_in[12];
    const float* Wq_s    = (const float*)d_in[13];
    const float* bq_s    = (const float*)d_in[14];
    const float* Wm_s    = (const float*)d_in[15];
    const float* v_s     = (const float*)d_in[16];
    const float* Wq_a    = (const float*)d_in[17];
    const float* bq_a    = (const float*)d_in[18];
    const float* Wm_a    = (const float*)d_in[19];
    const float* v_a     = (const float*)d_in[20];
    const float* Wq_sc   = (const float*)d_in[21];
    const float* bq_sc   = (const float*)d_in[22];
    const float* Wm_sc   = (const float*)d_in[23];
    const float* v_sc    = (const float*)d_in[24];
    const float* W_ih    = (const float*)d_in[25];
    const float* W_hh    = (const float*)d_in[26];
    const float* b_ih    = (const float*)d_in[27];
    const float* b_hh    = (const float*)d_in[28];
    const float* W_out   = (const float*)d_in[29];
    const float* b_out   = (const float*)d_in[30];

    float* out  = (float*)d_out;
    float* w    = (float*)d_ws;
    float* hnew = out + BV;
    unsigned short* sb = (unsigned short*)(w + FLOAT_TOTAL);

    float* qh_h = w + OFF_QH_H;  float* qh_s = w + OFF_QH_S;  float* qh_a = w + OFF_QH_A;
    float* qsc  = w + OFF_QSC;   float* gi   = w + OFF_GI;    float* gh   = w + OFF_GH;
    float* hsc  = w + OFF_HSC;   float* stsc = w + OFF_STSC;  float* acsc = w + OFF_ACSC;
    float* stlg = w + OFF_STLG;  float* aclg = w + OFF_ACLG;
    float* hsl  = w + OFF_HSL;   float* mbuf = w + OFF_M;     float* zbuf = w + OFF_Z;
    float* copyp = w + OFF_COPY;
    int*   ctr  = (int*)(w + OFF_CTR);
    int*   pfx  = (int*)(w + OFF_PFX);
    int*   ntb  = (int*)(w + OFF_NT);

    unsigned short* hs_bf = sb + SO_HS;   unsigned short* se_bf = sb + SO_SE;
    unsigned short* ae_bf = sb + SO_AE;   unsigned short* q0_bf = sb + SO_Q0;
    unsigned short* x_bf  = sb + SO_X;    unsigned short* hnb   = sb + SO_HNB;
    unsigned short* WqhT  = sb + SO_WQHT; unsigned short* WqsT  = sb + SO_WQST;
    unsigned short* WqaT  = sb + SO_WQAT; unsigned short* WqscT = sb + SO_WQSCT;
    unsigned short* WmhT  = sb + SO_WMHT; unsigned short* WmsT  = sb + SO_WMST;
    unsigned short* WmaT  = sb + SO_WMAT; unsigned short* WmscT = sb + SO_WMSCT;
    unsigned short* mseh  = sb + SO_MSE;  unsigned short* maeh  = sb + SO_MAE;

    dim3 blk(256);

    hipMemsetAsync(w, 0, (size_t)ZERO_FLOATS * 4, stream);
    hipMemsetAsync(copyp, 0, (size_t)BV * 4, stream);

    // fused prep: transpose-cvt 8 weights + lens prefix + cvt hs/se/ae/hidden
    PrepArgs pa;
    pa.cs[0]=hs; pa.cs[1]=se; pa.cs[2]=ae; pa.cs[3]=hidden;
    pa.cd[0]=hs_bf; pa.cd[1]=se_bf; pa.cd[2]=ae_bf; pa.cd[3]=q0_bf;
    pa.pre[0]=0; pa.pre[1]=4194304; pa.pre[2]=4358144; pa.pre[3]=4521984; pa.pre[4]=4538368;
    pa.ts[0]=Wq_hist; pa.ts[1]=Wq_s; pa.ts[2]=Wq_a; pa.ts[3]=Wq_sc;
    pa.ts[4]=Wm_hist; pa.ts[5]=Wm_s; pa.ts[6]=Wm_a; pa.ts[7]=Wm_sc;
    pa.td[0]=WqhT; pa.td[1]=WqsT; pa.td[2]=WqaT; pa.td[3]=WqscT;
    pa.td[4]=WmhT; pa.td[5]=WmsT; pa.td[6]=WmaT; pa.td[7]=WmscT;
    pa.lens = lens; pa.prefix = pfx; pa.nt = ntb;
    k_prep<<<dim3(4097), blk, 0, stream>>>(pa);

    // q-projections (split-K atomic, bias folded into consumers)
    k_qh4<<<dim3(8, 4, 3), blk, 0, stream>>>(q0_bf, WqhT, WqsT, WqaT, qh_h, qh_s, qh_a);

    // att scores + stac pre-activations + hist (compact): persistent queue
    BigArgs ba;
    ba.hs = hs_bf; ba.WmhT = WmhT; ba.se = se_bf; ba.ae = ae_bf;
    ba.WmsT = WmsT; ba.WmaT = WmaT; ba.WmscT = WmscT;
    ba.qh_h = qh_h; ba.bq_h = bq_hist; ba.v_h = v_hist;
    ba.qh_s = qh_s; ba.bq_s = bq_s; ba.v_s = v_s;
    ba.qh_a = qh_a; ba.bq_a = bq_a; ba.v_a = v_a;
    ba.hsc = hsc; ba.stsc = stsc; ba.acsc = acsc;
    ba.mseh = mseh; ba.maeh = maeh;
    k_big<<<dim3(256), dim3(512), 0, stream>>>(ba, ctr, pfx, ntb);

    // contexts -> x (bf16)
    k_ctx<<<dim3(128), blk, 0, stream>>>(hsc, lens, pfx, hs_bf, inp, stsc, acsc, se_bf, ae_bf, x_bf);
    // GRU gates (B staged directly from f32 weights)
    k_gigh2<<<dim3(24, 8, 2), blk, 0, stream>>>(x_bf, q0_bf, W_ih, W_hh, gi, gh);
    // GRU elementwise + hs logits (split over l)
    k_gruhsl<<<dim3(128, 2), dim3(1024), 0, stream>>>(gi, gh, b_ih, b_hh, hidden, hnew, hnb, hs_bf, hsl);
    // copy-scorer query + gene logits
    k_qsc_gene<<<dim3(329), blk, 0, stream>>>(hnb, WqscT, qsc, W_out, b_out, out);
    // stac logits (parallel epilogue over mseh/maeh)
    k_stacep<<<dim3(128), blk, 0, stream>>>(mseh, maeh, qsc, bq_sc, v_sc,
                                            Wm_sc + (size_t)1024 * 1024, stlg, aclg);
    // softmax stats + scatter, then fused final
    k_smsc<<<dim3(128), blk, 0, stream>>>(out, hsl, stlg, aclg, hwi, mbuf, zbuf, copyp);
    k_final<<<dim3(40, 128), blk, 0, stream>>>(out, copyp, sprob, aprob, stlg, aclg, mbuf, zbuf);

    (void)in_sizes; (void)n_in; (void)out_size; (void)ws_size;
}